// Round 5
// baseline (584.227 us; speedup 1.0000x reference)
//
#include <hip/hip_runtime.h>
#include <hip/hip_bf16.h>

#define NE 8
#define NT 512
#define DIN 7168
#define DINT 2048
#define BK 64

typedef __bf16 bf16x8 __attribute__((ext_vector_type(8)));
typedef float f32x4 __attribute__((ext_vector_type(4)));
typedef unsigned short ushort8v __attribute__((ext_vector_type(8)));

// XOR swizzle (T2): 16B granule within a 128B row XOR'd with row&7.
// row stride = 64 bf16 elements (128B).
__device__ __forceinline__ int swz(int row, int k) {
    return (row << 6) + (((k >> 3) ^ (row & 7)) << 3) + (k & 7);
}

__device__ __forceinline__ ushort4 cvt4(float4 v) {
    ushort4 h;
    h.x = __builtin_bit_cast(unsigned short, (__bf16)v.x);
    h.y = __builtin_bit_cast(unsigned short, (__bf16)v.y);
    h.z = __builtin_bit_cast(unsigned short, (__bf16)v.z);
    h.w = __builtin_bit_cast(unsigned short, (__bf16)v.w);
    return h;
}

// ---------------- Kernel A: gate+up ----------------
// BM=256 x BN=128, BK=64, 512 threads = 8 waves (4x2), wave-tile 64x64,
// dual acc. grid (16,2,8) = 256 blocks = 1/CU. Double-buffered LDS (128 KB).
// Iter order: stage(t+1) -> issue prefetch(t+2) -> compute(t) -> barrier,
// so prefetch loads are in flight for the whole compute phase before the
// barrier's vmcnt(0) drain.
__global__ __launch_bounds__(512, 2) void ffn_gate_up(
    const float* __restrict__ x, const float* __restrict__ w1,
    const float* __restrict__ b1, const float* __restrict__ w3,
    const float* __restrict__ b3, unsigned short* __restrict__ g) {
    __shared__ unsigned short As[2][256 * BK];   // 2x32 KB
    __shared__ unsigned short B1s[2][128 * BK];  // 2x16 KB
    __shared__ unsigned short B3s[2][128 * BK];  // 2x16 KB

    const int tid = threadIdx.x;
    const int lane = tid & 63;
    const int wave = tid >> 6;
    const int wm = wave >> 1, wn = wave & 1;  // wave tile 64(M) x 64(N)
    const int e = blockIdx.z;
    const int bn = blockIdx.x * 128;
    const int bm = blockIdx.y * 256;

    const float* xA = x + (size_t)e * NT * DIN + (size_t)bm * DIN;
    const float* w1B = w1 + (size_t)e * DINT * DIN + (size_t)bn * DIN;
    const float* w3B = w3 + (size_t)e * DINT * DIN + (size_t)bn * DIN;

    f32x4 acc1[4][4], acc3[4][4];
#pragma unroll
    for (int m = 0; m < 4; ++m)
#pragma unroll
        for (int n = 0; n < 4; ++n) {
            acc1[m][n] = (f32x4)0.0f;
            acc3[m][n] = (f32x4)0.0f;
        }

    const int srow = tid >> 4;        // 0..31
    const int scol = (tid & 15) * 4;  // 0..60

    float4 ra[8], rb1[4], rb3[4];

    // prologue: tile0 -> regs -> buf0 ; tile1 -> regs
#pragma unroll
    for (int p = 0; p < 8; ++p)
        ra[p] = *(const float4*)(xA + (size_t)(p * 32 + srow) * DIN + scol);
#pragma unroll
    for (int p = 0; p < 4; ++p) {
        rb1[p] = *(const float4*)(w1B + (size_t)(p * 32 + srow) * DIN + scol);
        rb3[p] = *(const float4*)(w3B + (size_t)(p * 32 + srow) * DIN + scol);
    }
#pragma unroll
    for (int p = 0; p < 8; ++p)
        *(ushort4*)&As[0][swz(p * 32 + srow, scol)] = cvt4(ra[p]);
#pragma unroll
    for (int p = 0; p < 4; ++p) {
        *(ushort4*)&B1s[0][swz(p * 32 + srow, scol)] = cvt4(rb1[p]);
        *(ushort4*)&B3s[0][swz(p * 32 + srow, scol)] = cvt4(rb3[p]);
    }
#pragma unroll
    for (int p = 0; p < 8; ++p)
        ra[p] = *(const float4*)(xA + (size_t)(p * 32 + srow) * DIN + BK + scol);
#pragma unroll
    for (int p = 0; p < 4; ++p) {
        rb1[p] = *(const float4*)(w1B + (size_t)(p * 32 + srow) * DIN + BK + scol);
        rb3[p] = *(const float4*)(w3B + (size_t)(p * 32 + srow) * DIN + BK + scol);
    }
    __syncthreads();

    int cur = 0;
    const int NIT = DIN / BK;  // 112
    for (int t = 0; t < NIT - 1; ++t) {
        const int nxt = cur ^ 1;
        // ---- stage tile t+1 -> buf[nxt] (vmcnt-gated; loads issued iter t-1) ----
#pragma unroll
        for (int p = 0; p < 8; ++p)
            *(ushort4*)&As[nxt][swz(p * 32 + srow, scol)] = cvt4(ra[p]);
#pragma unroll
        for (int p = 0; p < 4; ++p) {
            *(ushort4*)&B1s[nxt][swz(p * 32 + srow, scol)] = cvt4(rb1[p]);
            *(ushort4*)&B3s[nxt][swz(p * 32 + srow, scol)] = cvt4(rb3[p]);
        }
        // ---- issue prefetch of tile t+2 (in flight during compute) ----
        const int kld = min((t + 2) * BK, DIN - BK);
#pragma unroll
        for (int p = 0; p < 8; ++p)
            ra[p] = *(const float4*)(xA + (size_t)(p * 32 + srow) * DIN + kld + scol);
#pragma unroll
        for (int p = 0; p < 4; ++p) {
            rb1[p] = *(const float4*)(w1B + (size_t)(p * 32 + srow) * DIN + kld + scol);
            rb3[p] = *(const float4*)(w3B + (size_t)(p * 32 + srow) * DIN + kld + scol);
        }
        // pin: keep the load issues above the compute section
        __builtin_amdgcn_sched_barrier(0);
        // ---- compute tile t from buf[cur] ----
#pragma unroll
        for (int ks = 0; ks < 2; ++ks) {
            const int kf = ks * 32 + ((lane >> 4) << 3);
            bf16x8 b1f[4], b3f[4];
#pragma unroll
            for (int n = 0; n < 4; ++n) {
                const int row = wn * 64 + n * 16 + (lane & 15);
                b1f[n] = *(const bf16x8*)&B1s[cur][swz(row, kf)];
                b3f[n] = *(const bf16x8*)&B3s[cur][swz(row, kf)];
            }
#pragma unroll
            for (int m = 0; m < 4; ++m) {
                const bf16x8 af = *(const bf16x8*)&As[cur][swz(wm * 64 + m * 16 + (lane & 15), kf)];
#pragma unroll
                for (int n = 0; n < 4; ++n) {
                    acc1[m][n] = __builtin_amdgcn_mfma_f32_16x16x32_bf16(af, b1f[n], acc1[m][n], 0, 0, 0);
                    acc3[m][n] = __builtin_amdgcn_mfma_f32_16x16x32_bf16(af, b3f[n], acc3[m][n], 0, 0, 0);
                }
            }
        }
        __syncthreads();
        cur = nxt;
    }
    // ---- final tile ----
#pragma unroll
    for (int ks = 0; ks < 2; ++ks) {
        const int kf = ks * 32 + ((lane >> 4) << 3);
        bf16x8 b1f[4], b3f[4];
#pragma unroll
        for (int n = 0; n < 4; ++n) {
            const int row = wn * 64 + n * 16 + (lane & 15);
            b1f[n] = *(const bf16x8*)&B1s[cur][swz(row, kf)];
            b3f[n] = *(const bf16x8*)&B3s[cur][swz(row, kf)];
        }
#pragma unroll
        for (int m = 0; m < 4; ++m) {
            const bf16x8 af = *(const bf16x8*)&As[cur][swz(wm * 64 + m * 16 + (lane & 15), kf)];
#pragma unroll
            for (int n = 0; n < 4; ++n) {
                acc1[m][n] = __builtin_amdgcn_mfma_f32_16x16x32_bf16(af, b1f[n], acc1[m][n], 0, 0, 0);
                acc3[m][n] = __builtin_amdgcn_mfma_f32_16x16x32_bf16(af, b3f[n], acc3[m][n], 0, 0, 0);
            }
        }
    }

    // epilogue: bias + silu*mul -> bf16 g
    float bias1[4], bias3[4];
#pragma unroll
    for (int n = 0; n < 4; ++n) {
        const int f = bn + wn * 64 + n * 16 + (lane & 15);
        bias1[n] = b1[e * DINT + f];
        bias3[n] = b3[e * DINT + f];
    }
#pragma unroll
    for (int m = 0; m < 4; ++m)
#pragma unroll
        for (int n = 0; n < 4; ++n) {
            const int f = bn + wn * 64 + n * 16 + (lane & 15);
#pragma unroll
            for (int j = 0; j < 4; ++j) {
                const int t = bm + wm * 64 + m * 16 + ((lane >> 4) << 2) + j;
                const float h1 = acc1[m][n][j] + bias1[n];
                const float h3 = acc3[m][n][j] + bias3[n];
                const float sg = h1 / (1.0f + __expf(-h1));
                g[(size_t)e * NT * DINT + (size_t)t * DINT + f] =
                    __builtin_bit_cast(unsigned short, (__bf16)(sg * h3));
            }
        }
}

// ---------------- Kernel B: down ----------------
// BM=256 x BN=128, BK=64, 512 threads, wave-tile 64x64. grid (56,2,8)=896.
// Same stage -> prefetch -> compute -> barrier structure; LDS 96 KB.
__global__ __launch_bounds__(512, 2) void ffn_down(
    const unsigned short* __restrict__ g, const float* __restrict__ w2,
    const float* __restrict__ b2, float* __restrict__ out) {
    __shared__ unsigned short As[2][256 * BK];  // 2x32 KB
    __shared__ unsigned short Bs[2][128 * BK];  // 2x16 KB

    const int tid = threadIdx.x;
    const int lane = tid & 63;
    const int wave = tid >> 6;
    const int wm = wave >> 1, wn = wave & 1;
    const int e = blockIdx.z;
    const int bn = blockIdx.x * 128;
    const int bm = blockIdx.y * 256;

    const unsigned short* gA = g + (size_t)e * NT * DINT + (size_t)bm * DINT;
    const float* w2B = w2 + (size_t)e * DIN * DINT + (size_t)bn * DINT;

    f32x4 acc[4][4];
#pragma unroll
    for (int m = 0; m < 4; ++m)
#pragma unroll
        for (int n = 0; n < 4; ++n) acc[m][n] = (f32x4)0.0f;

    const int arow = tid >> 3;        // 0..63
    const int acol = (tid & 7) * 8;   // bf16 elems
    const int brow = tid >> 4;        // 0..31
    const int bcol = (tid & 15) * 4;

    ushort8v ga[4];
    float4 rb[4];

#pragma unroll
    for (int p = 0; p < 4; ++p)
        ga[p] = *(const ushort8v*)(gA + (size_t)(p * 64 + arow) * DINT + acol);
#pragma unroll
    for (int p = 0; p < 4; ++p)
        rb[p] = *(const float4*)(w2B + (size_t)(p * 32 + brow) * DINT + bcol);
#pragma unroll
    for (int p = 0; p < 4; ++p)
        *(ushort8v*)&As[0][swz(p * 64 + arow, acol)] = ga[p];
#pragma unroll
    for (int p = 0; p < 4; ++p)
        *(ushort4*)&Bs[0][swz(p * 32 + brow, bcol)] = cvt4(rb[p]);
#pragma unroll
    for (int p = 0; p < 4; ++p)
        ga[p] = *(const ushort8v*)(gA + (size_t)(p * 64 + arow) * DINT + BK + acol);
#pragma unroll
    for (int p = 0; p < 4; ++p)
        rb[p] = *(const float4*)(w2B + (size_t)(p * 32 + brow) * DINT + BK + bcol);
    __syncthreads();

    int cur = 0;
    const int NIT = DINT / BK;  // 32
    for (int t = 0; t < NIT - 1; ++t) {
        const int nxt = cur ^ 1;
#pragma unroll
        for (int p = 0; p < 4; ++p)
            *(ushort8v*)&As[nxt][swz(p * 64 + arow, acol)] = ga[p];
#pragma unroll
        for (int p = 0; p < 4; ++p)
            *(ushort4*)&Bs[nxt][swz(p * 32 + brow, bcol)] = cvt4(rb[p]);
        const int kld = min((t + 2) * BK, DINT - BK);
#pragma unroll
        for (int p = 0; p < 4; ++p)
            ga[p] = *(const ushort8v*)(gA + (size_t)(p * 64 + arow) * DINT + kld + acol);
#pragma unroll
        for (int p = 0; p < 4; ++p)
            rb[p] = *(const float4*)(w2B + (size_t)(p * 32 + brow) * DINT + kld + bcol);
        __builtin_amdgcn_sched_barrier(0);
#pragma unroll
        for (int ks = 0; ks < 2; ++ks) {
            const int kf = ks * 32 + ((lane >> 4) << 3);
            bf16x8 bf[4];
#pragma unroll
            for (int n = 0; n < 4; ++n)
                bf[n] = *(const bf16x8*)&Bs[cur][swz(wn * 64 + n * 16 + (lane & 15), kf)];
#pragma unroll
            for (int m = 0; m < 4; ++m) {
                const bf16x8 af = *(const bf16x8*)&As[cur][swz(wm * 64 + m * 16 + (lane & 15), kf)];
#pragma unroll
                for (int n = 0; n < 4; ++n)
                    acc[m][n] = __builtin_amdgcn_mfma_f32_16x16x32_bf16(af, bf[n], acc[m][n], 0, 0, 0);
            }
        }
        __syncthreads();
        cur = nxt;
    }
#pragma unroll
    for (int ks = 0; ks < 2; ++ks) {
        const int kf = ks * 32 + ((lane >> 4) << 3);
        bf16x8 bf[4];
#pragma unroll
        for (int n = 0; n < 4; ++n)
            bf[n] = *(const bf16x8*)&Bs[cur][swz(wn * 64 + n * 16 + (lane & 15), kf)];
#pragma unroll
        for (int m = 0; m < 4; ++m) {
            const bf16x8 af = *(const bf16x8*)&As[cur][swz(wm * 64 + m * 16 + (lane & 15), kf)];
#pragma unroll
            for (int n = 0; n < 4; ++n)
                acc[m][n] = __builtin_amdgcn_mfma_f32_16x16x32_bf16(af, bf[n], acc[m][n], 0, 0, 0);
        }
    }

    float bias[4];
#pragma unroll
    for (int n = 0; n < 4; ++n) {
        const int d = bn + wn * 64 + n * 16 + (lane & 15);
        bias[n] = b2[e * DIN + d];
    }
#pragma unroll
    for (int m = 0; m < 4; ++m)
#pragma unroll
        for (int n = 0; n < 4; ++n) {
            const int d = bn + wn * 64 + n * 16 + (lane & 15);
#pragma unroll
            for (int j = 0; j < 4; ++j) {
                const int t = bm + wm * 64 + m * 16 + ((lane >> 4) << 2) + j;
                out[(size_t)e * NT * DIN + (size_t)t * DIN + d] = acc[m][n][j] + bias[n];
            }
        }
}

extern "C" void kernel_launch(void* const* d_in, const int* in_sizes, int n_in,
                              void* d_out, int out_size, void* d_ws, size_t ws_size,
                              hipStream_t stream) {
    const float* x = (const float*)d_in[0];
    const float* w1 = (const float*)d_in[1];
    const float* b1 = (const float*)d_in[2];
    const float* w3 = (const float*)d_in[3];
    const float* b3 = (const float*)d_in[4];
    const float* w2 = (const float*)d_in[5];
    const float* b2 = (const float*)d_in[6];
    float* out = (float*)d_out;
    unsigned short* g = (unsigned short*)d_ws;  // [E][T][DINT] bf16

    dim3 gridA(DINT / 128, NT / 256, NE);  // (16, 2, 8) = 256 blocks
    dim3 gridB(DIN / 128, NT / 256, NE);   // (56, 2, 8) = 896 blocks
    ffn_gate_up<<<gridA, dim3(512), 0, stream>>>(x, w1, b1, w3, b3, g);
    ffn_down<<<gridB, dim3(512), 0, stream>>>(g, w2, b2, out);
}

// Round 6
// 502.012 us; speedup vs baseline: 1.1638x; 1.1638x over previous
//
#include <hip/hip_runtime.h>
#include <hip/hip_bf16.h>

#define NE 8
#define NT 512
#define DIN 7168
#define DINT 2048
#define BK 64

typedef __bf16 bf16x8 __attribute__((ext_vector_type(8)));
typedef float f32x4 __attribute__((ext_vector_type(4)));
typedef unsigned short ushort8v __attribute__((ext_vector_type(8)));

#define MFMA __builtin_amdgcn_mfma_f32_16x16x32_bf16

// XOR swizzle (T2): 16B granule within a 128B row XOR'd with row&7.
// row stride = 64 bf16 elements (128B).
__device__ __forceinline__ int swz(int row, int k) {
    return (row << 6) + (((k >> 3) ^ (row & 7)) << 3) + (k & 7);
}

__device__ __forceinline__ ushort4 cvt4(float4 v) {
    ushort4 h;
    h.x = __builtin_bit_cast(unsigned short, (__bf16)v.x);
    h.y = __builtin_bit_cast(unsigned short, (__bf16)v.y);
    h.z = __builtin_bit_cast(unsigned short, (__bf16)v.z);
    h.w = __builtin_bit_cast(unsigned short, (__bf16)v.w);
    return h;
}

// lgkm-only drain + raw barrier: outstanding global loads (vmcnt) are NOT
// drained -- they stay in flight across the barrier (T4). LDS visibility
// needs only lgkmcnt(0).
__device__ __forceinline__ void barrier_lgkm() {
    asm volatile("s_waitcnt lgkmcnt(0)" ::: "memory");
    __builtin_amdgcn_s_barrier();
}

// ---------------- Kernel A: gate+up ----------------
// BM=256 x BN=128, BK=64, 512 thr = 8 waves (4x2), wave 64x64, dual acc.
// grid (16,2,8)=256 = 1 block/CU. dbuf LDS 128 KB. 4 phases per K-tile,
// each: {ds_read frags | 1/4 ds_writes(t+1) | 1/4 load-issue(t+2) |
// setprio(1) 16xMFMA setprio(0)}; one lgkm+s_barrier per K-tile.
__global__ __launch_bounds__(512, 2) void ffn_gate_up(
    const float* __restrict__ x, const float* __restrict__ w1,
    const float* __restrict__ b1, const float* __restrict__ w3,
    const float* __restrict__ b3, unsigned short* __restrict__ g) {
    __shared__ unsigned short As[2][256 * BK];   // 64 KB
    __shared__ unsigned short B1s[2][128 * BK];  // 32 KB
    __shared__ unsigned short B3s[2][128 * BK];  // 32 KB

    const int tid = threadIdx.x;
    const int lane = tid & 63;
    const int wave = tid >> 6;
    const int wm = wave >> 1, wn = wave & 1;
    const int e = blockIdx.z;
    const int bn = blockIdx.x * 128;
    const int bm = blockIdx.y * 256;

    const char* xb = (const char*)x + ((size_t)e * NT * DIN + (size_t)bm * DIN) * 4;
    const char* w1c = (const char*)w1 + ((size_t)e * DINT * DIN + (size_t)bn * DIN) * 4;
    const char* w3c = (const char*)w3 + ((size_t)e * DINT * DIN + (size_t)bn * DIN) * 4;

    const int srow = tid >> 4;          // 0..31
    const int scol = (tid & 15) * 4;    // 0..60
    const int swb = swz(srow, scol);    // p-invariant: (p*32+srow)&7 == srow&7

    int xo[8];  // loop-invariant byte offsets (saddr form)
#pragma unroll
    for (int p = 0; p < 8; ++p) xo[p] = ((p * 32 + srow) * DIN + scol) * 4;

    f32x4 acc1[4][4], acc3[4][4];
#pragma unroll
    for (int m = 0; m < 4; ++m)
#pragma unroll
        for (int n = 0; n < 4; ++n) {
            acc1[m][n] = (f32x4)0.0f;
            acc3[m][n] = (f32x4)0.0f;
        }

    float4 ra[8], rb1[4], rb3[4];

    // prologue: tile0 -> regs -> buf0; tile1 -> regs
#pragma unroll
    for (int p = 0; p < 8; ++p) ra[p] = *(const float4*)(xb + xo[p]);
#pragma unroll
    for (int p = 0; p < 4; ++p) {
        rb1[p] = *(const float4*)(w1c + xo[p]);
        rb3[p] = *(const float4*)(w3c + xo[p]);
    }
#pragma unroll
    for (int p = 0; p < 8; ++p) *(ushort4*)&As[0][p * 2048 + swb] = cvt4(ra[p]);
#pragma unroll
    for (int p = 0; p < 4; ++p) {
        *(ushort4*)&B1s[0][p * 2048 + swb] = cvt4(rb1[p]);
        *(ushort4*)&B3s[0][p * 2048 + swb] = cvt4(rb3[p]);
    }
#pragma unroll
    for (int p = 0; p < 8; ++p) ra[p] = *(const float4*)(xb + xo[p] + BK * 4);
#pragma unroll
    for (int p = 0; p < 4; ++p) {
        rb1[p] = *(const float4*)(w1c + xo[p] + BK * 4);
        rb3[p] = *(const float4*)(w3c + xo[p] + BK * 4);
    }
    barrier_lgkm();

    const int l15 = lane & 15;
    const int kf0 = (lane >> 4) << 3;

    int cur = 0;
    const int NIT = DIN / BK;  // 112
    for (int t = 0; t < NIT; ++t) {
        const int nxt = cur ^ 1;
        const int kldB = ((t + 2 < NIT) ? (t + 2) * BK : (NIT - 1) * BK) * 4;
        const bool stage = (t < NIT - 1);
        bf16x8 af[4], bb[4];

        // ---- Phase 0: A@ks0 + B1@ks0 -> acc1 ----
#pragma unroll
        for (int m = 0; m < 4; ++m)
            af[m] = *(const bf16x8*)&As[cur][swz(wm * 64 + m * 16 + l15, kf0)];
#pragma unroll
        for (int n = 0; n < 4; ++n)
            bb[n] = *(const bf16x8*)&B1s[cur][swz(wn * 64 + n * 16 + l15, kf0)];
        if (stage) {
#pragma unroll
            for (int p = 0; p < 4; ++p) *(ushort4*)&As[nxt][p * 2048 + swb] = cvt4(ra[p]);
#pragma unroll
            for (int p = 0; p < 4; ++p) ra[p] = *(const float4*)(xb + xo[p] + kldB);
        }
        __builtin_amdgcn_s_setprio(1);
#pragma unroll
        for (int n = 0; n < 4; ++n)
#pragma unroll
            for (int m = 0; m < 4; ++m)
                acc1[m][n] = MFMA(af[m], bb[n], acc1[m][n], 0, 0, 0);
        __builtin_amdgcn_s_setprio(0);
        __builtin_amdgcn_sched_barrier(0);

        // ---- Phase 1: B3@ks0 -> acc3 (reuse af) ----
#pragma unroll
        for (int n = 0; n < 4; ++n)
            bb[n] = *(const bf16x8*)&B3s[cur][swz(wn * 64 + n * 16 + l15, kf0)];
        if (stage) {
#pragma unroll
            for (int p = 4; p < 8; ++p) *(ushort4*)&As[nxt][p * 2048 + swb] = cvt4(ra[p]);
#pragma unroll
            for (int p = 4; p < 8; ++p) ra[p] = *(const float4*)(xb + xo[p] + kldB);
        }
        __builtin_amdgcn_s_setprio(1);
#pragma unroll
        for (int n = 0; n < 4; ++n)
#pragma unroll
            for (int m = 0; m < 4; ++m)
                acc3[m][n] = MFMA(af[m], bb[n], acc3[m][n], 0, 0, 0);
        __builtin_amdgcn_s_setprio(0);
        __builtin_amdgcn_sched_barrier(0);

        // ---- Phase 2: A@ks1 + B1@ks1 -> acc1 ----
#pragma unroll
        for (int m = 0; m < 4; ++m)
            af[m] = *(const bf16x8*)&As[cur][swz(wm * 64 + m * 16 + l15, 32 + kf0)];
#pragma unroll
        for (int n = 0; n < 4; ++n)
            bb[n] = *(const bf16x8*)&B1s[cur][swz(wn * 64 + n * 16 + l15, 32 + kf0)];
        if (stage) {
#pragma unroll
            for (int p = 0; p < 4; ++p) *(ushort4*)&B1s[nxt][p * 2048 + swb] = cvt4(rb1[p]);
#pragma unroll
            for (int p = 0; p < 4; ++p) rb1[p] = *(const float4*)(w1c + xo[p] + kldB);
        }
        __builtin_amdgcn_s_setprio(1);
#pragma unroll
        for (int n = 0; n < 4; ++n)
#pragma unroll
            for (int m = 0; m < 4; ++m)
                acc1[m][n] = MFMA(af[m], bb[n], acc1[m][n], 0, 0, 0);
        __builtin_amdgcn_s_setprio(0);
        __builtin_amdgcn_sched_barrier(0);

        // ---- Phase 3: B3@ks1 -> acc3 ----
#pragma unroll
        for (int n = 0; n < 4; ++n)
            bb[n] = *(const bf16x8*)&B3s[cur][swz(wn * 64 + n * 16 + l15, 32 + kf0)];
        if (stage) {
#pragma unroll
            for (int p = 0; p < 4; ++p) *(ushort4*)&B3s[nxt][p * 2048 + swb] = cvt4(rb3[p]);
#pragma unroll
            for (int p = 0; p < 4; ++p) rb3[p] = *(const float4*)(w3c + xo[p] + kldB);
        }
        __builtin_amdgcn_s_setprio(1);
#pragma unroll
        for (int n = 0; n < 4; ++n)
#pragma unroll
            for (int m = 0; m < 4; ++m)
                acc3[m][n] = MFMA(af[m], bb[n], acc3[m][n], 0, 0, 0);
        __builtin_amdgcn_s_setprio(0);

        barrier_lgkm();
        cur = nxt;
    }

    // epilogue: bias + silu*mul -> bf16 g
    float bias1[4], bias3[4];
#pragma unroll
    for (int n = 0; n < 4; ++n) {
        const int f = bn + wn * 64 + n * 16 + l15;
        bias1[n] = b1[e * DINT + f];
        bias3[n] = b3[e * DINT + f];
    }
#pragma unroll
    for (int m = 0; m < 4; ++m)
#pragma unroll
        for (int n = 0; n < 4; ++n) {
            const int f = bn + wn * 64 + n * 16 + l15;
#pragma unroll
            for (int j = 0; j < 4; ++j) {
                const int t = bm + wm * 64 + m * 16 + ((lane >> 4) << 2) + j;
                const float h1 = acc1[m][n][j] + bias1[n];
                const float h3 = acc3[m][n][j] + bias3[n];
                const float sg = h1 / (1.0f + __expf(-h1));
                g[(size_t)e * NT * DINT + (size_t)t * DINT + f] =
                    __builtin_bit_cast(unsigned short, (__bf16)(sg * h3));
            }
        }
}

// ---------------- Kernel B: down ----------------
// BM=256 x BN=128, 512 thr, wave 64x64. grid (56,2,8)=896. dbuf 96 KB.
// 2 phases per K-tile (ks=0,1), each 16 MFMA + half the staging.
__global__ __launch_bounds__(512, 2) void ffn_down(
    const unsigned short* __restrict__ g, const float* __restrict__ w2,
    const float* __restrict__ b2, float* __restrict__ out) {
    __shared__ unsigned short As[2][256 * BK];  // 64 KB
    __shared__ unsigned short Bs[2][128 * BK];  // 32 KB

    const int tid = threadIdx.x;
    const int lane = tid & 63;
    const int wave = tid >> 6;
    const int wm = wave >> 1, wn = wave & 1;
    const int e = blockIdx.z;
    const int bn = blockIdx.x * 128;
    const int bm = blockIdx.y * 256;

    const char* gc = (const char*)g + ((size_t)e * NT * DINT + (size_t)bm * DINT) * 2;
    const char* w2c = (const char*)w2 + ((size_t)e * DIN * DINT + (size_t)bn * DINT) * 4;

    const int arow = tid >> 3;          // 0..63
    const int acol = (tid & 7) * 8;     // bf16 elems
    const int brow = tid >> 4;          // 0..31
    const int bcol = (tid & 15) * 4;
    const int swA = swz(arow, acol);    // p-invariant ((p*64+arow)&7 == arow&7)
    const int swB = swz(brow, bcol);

    int go[4], wo[4];
#pragma unroll
    for (int p = 0; p < 4; ++p) {
        go[p] = ((p * 64 + arow) * DINT + acol) * 2;
        wo[p] = ((p * 32 + brow) * DINT + bcol) * 4;
    }

    f32x4 acc[4][4];
#pragma unroll
    for (int m = 0; m < 4; ++m)
#pragma unroll
        for (int n = 0; n < 4; ++n) acc[m][n] = (f32x4)0.0f;

    ushort8v ga[4];
    float4 rb[4];

#pragma unroll
    for (int p = 0; p < 4; ++p) ga[p] = *(const ushort8v*)(gc + go[p]);
#pragma unroll
    for (int p = 0; p < 4; ++p) rb[p] = *(const float4*)(w2c + wo[p]);
#pragma unroll
    for (int p = 0; p < 4; ++p) *(ushort8v*)&As[0][p * 4096 + swA] = ga[p];
#pragma unroll
    for (int p = 0; p < 4; ++p) *(ushort4*)&Bs[0][p * 2048 + swB] = cvt4(rb[p]);
#pragma unroll
    for (int p = 0; p < 4; ++p) ga[p] = *(const ushort8v*)(gc + go[p] + BK * 2);
#pragma unroll
    for (int p = 0; p < 4; ++p) rb[p] = *(const float4*)(w2c + wo[p] + BK * 4);
    barrier_lgkm();

    const int l15 = lane & 15;
    const int kf0 = (lane >> 4) << 3;

    int cur = 0;
    const int NIT = DINT / BK;  // 32
    for (int t = 0; t < NIT; ++t) {
        const int nxt = cur ^ 1;
        const int kld = (t + 2 < NIT) ? (t + 2) * BK : (NIT - 1) * BK;
        const bool stage = (t < NIT - 1);
        bf16x8 af[4], bf[4];

        // ---- Phase 0: ks0 ----
#pragma unroll
        for (int m = 0; m < 4; ++m)
            af[m] = *(const bf16x8*)&As[cur][swz(wm * 64 + m * 16 + l15, kf0)];
#pragma unroll
        for (int n = 0; n < 4; ++n)
            bf[n] = *(const bf16x8*)&Bs[cur][swz(wn * 64 + n * 16 + l15, kf0)];
        if (stage) {
#pragma unroll
            for (int p = 0; p < 4; ++p) *(ushort8v*)&As[nxt][p * 4096 + swA] = ga[p];
#pragma unroll
            for (int p = 0; p < 4; ++p) ga[p] = *(const ushort8v*)(gc + go[p] + kld * 2);
        }
        __builtin_amdgcn_s_setprio(1);
#pragma unroll
        for (int n = 0; n < 4; ++n)
#pragma unroll
            for (int m = 0; m < 4; ++m)
                acc[m][n] = MFMA(af[m], bf[n], acc[m][n], 0, 0, 0);
        __builtin_amdgcn_s_setprio(0);
        __builtin_amdgcn_sched_barrier(0);

        // ---- Phase 1: ks1 ----
#pragma unroll
        for (int m = 0; m < 4; ++m)
            af[m] = *(const bf16x8*)&As[cur][swz(wm * 64 + m * 16 + l15, 32 + kf0)];
#pragma unroll
        for (int n = 0; n < 4; ++n)
            bf[n] = *(const bf16x8*)&Bs[cur][swz(wn * 64 + n * 16 + l15, 32 + kf0)];
        if (stage) {
#pragma unroll
            for (int p = 0; p < 4; ++p) *(ushort4*)&Bs[nxt][p * 2048 + swB] = cvt4(rb[p]);
#pragma unroll
            for (int p = 0; p < 4; ++p) rb[p] = *(const float4*)(w2c + wo[p] + kld * 4);
        }
        __builtin_amdgcn_s_setprio(1);
#pragma unroll
        for (int n = 0; n < 4; ++n)
#pragma unroll
            for (int m = 0; m < 4; ++m)
                acc[m][n] = MFMA(af[m], bf[n], acc[m][n], 0, 0, 0);
        __builtin_amdgcn_s_setprio(0);

        barrier_lgkm();
        cur = nxt;
    }

    float bias[4];
#pragma unroll
    for (int n = 0; n < 4; ++n) {
        const int d = bn + wn * 64 + n * 16 + l15;
        bias[n] = b2[e * DIN + d];
    }
#pragma unroll
    for (int m = 0; m < 4; ++m)
#pragma unroll
        for (int n = 0; n < 4; ++n) {
            const int d = bn + wn * 64 + n * 16 + l15;
#pragma unroll
            for (int j = 0; j < 4; ++j) {
                const int t = bm + wm * 64 + m * 16 + ((lane >> 4) << 2) + j;
                out[(size_t)e * NT * DIN + (size_t)t * DIN + d] = acc[m][n][j] + bias[n];
            }
        }
}

extern "C" void kernel_launch(void* const* d_in, const int* in_sizes, int n_in,
                              void* d_out, int out_size, void* d_ws, size_t ws_size,
                              hipStream_t stream) {
    const float* x = (const float*)d_in[0];
    const float* w1 = (const float*)d_in[1];
    const float* b1 = (const float*)d_in[2];
    const float* w3 = (const float*)d_in[3];
    const float* b3 = (const float*)d_in[4];
    const float* w2 = (const float*)d_in[5];
    const float* b2 = (const float*)d_in[6];
    float* out = (float*)d_out;
    unsigned short* g = (unsigned short*)d_ws;  // [E][T][DINT] bf16

    dim3 gridA(DINT / 128, NT / 256, NE);  // (16, 2, 8) = 256 blocks
    dim3 gridB(DIN / 128, NT / 256, NE);   // (56, 2, 8) = 896 blocks
    ffn_gate_up<<<gridA, dim3(512), 0, stream>>>(x, w1, b1, w3, b3, g);
    ffn_down<<<gridB, dim3(512), 0, stream>>>(g, w2, b2, out);
}